// Round 2
// baseline (526.974 us; speedup 1.0000x reference)
//
#include <hip/hip_runtime.h>

// PPAModel: node encoder -> edge gather/concat -> edge MLP -> sigmoid
// IN=128, HID=256, OUT=128, N_NODES=100000, N_EDGES=1000000
//
// v12 (v10 + wide-MLP edge_pred; v11's nt hints + LDS alias reverted):
//   e@W3 = h_src@W3t + h_dst@W3b ;  h = relu1@W2
//   prep:   Wut=W2@W3t, Wvt=W2@W3b (bf16-swizzled), bu,bv, w4p (permuted W4)
//   node_uv: identical to v10 (296us-verified).
//   edge_pred: 16 edges per wave-iter (4 per 16-lane group) -> 16 independent
//     uint4 gathers per lane issued before any use (compiler cannot
//     re-serialize: all results live into compute). Next-iter INDEX prefetch
//     only. launch_bounds(256,5): 5 waves/SIMD x 16 loads = 80 in flight
//     vs v10's 8x8=64. No nontemporal hints anywhere (v11: +427MB HBM).
//
// ws layout (~103.5 MB):
//   flag @ 0          w1s @ 256 (64KB)
//   wuts @ 65792 (128KB)   wvts @ 196864 (128KB)
//   bu @ 327936 (1KB)      bv @ 328960 (1KB)    w4p @ 329984 (1KB)
//   U @ 1048576 (51.2MB)   V @ 52248576 (51.2MB)

#define NN 100000
#define NE 1000000
#define NTN 1563
#define GRID_EP 2048
#define STEP16 (((GRID_EP * 256) >> 6) * 16)  // 131072 edges per grid-stride round

typedef __attribute__((ext_vector_type(8))) __bf16 bf16x8;
typedef __attribute__((ext_vector_type(4))) float f32x4;
typedef __attribute__((ext_vector_type(4))) unsigned short us4;

__device__ __forceinline__ unsigned short f2bf(float f) {
    unsigned u = __float_as_uint(f);
    return (unsigned short)((u + 0x7FFFu + ((u >> 16) & 1u)) >> 16);
}
__device__ __forceinline__ float bflo(unsigned w) {
    return __uint_as_float(w << 16);
}
__device__ __forceinline__ float bfhi(unsigned w) {
    return __uint_as_float(w & 0xffff0000u);
}

template <int CTRL>
__device__ __forceinline__ float dpp_add(float v) {
    return v + __int_as_float(__builtin_amdgcn_update_dpp(
                   0, __float_as_int(v), CTRL, 0xF, 0xF, true));
}
// sum over 16 lanes of a DPP row; valid at (lane&15)==15 (row_shr -> high lane)
__device__ __forceinline__ float row_reduce16(float v) {
    v = dpp_add<0x118>(v);
    v = dpp_add<0x114>(v);
    v = dpp_add<0x112>(v);
    v = dpp_add<0x111>(v);
    return v;
}

// ---------------- prep: W1 swizzle, Wut/Wvt bf16-swizzled, bu/bv/w4p ------
__global__ void prep1(const float* __restrict__ W1, const float* __restrict__ W2,
                      const float* __restrict__ W3, const float* __restrict__ b2,
                      const float* __restrict__ b3, const float* __restrict__ W4,
                      const void* __restrict__ eidx,
                      unsigned short* __restrict__ w1s,
                      unsigned short* __restrict__ wuts,
                      unsigned short* __restrict__ wvts, float* __restrict__ bu,
                      float* __restrict__ bv, float* __restrict__ w4p,
                      int* __restrict__ flag) {
    int t = blockIdx.x * blockDim.x + threadIdx.x;  // 131072 threads
    if (t < 32768) {  // W1 swizzle: K=128, N=256, [k/8][n][k%8]
        int k = t >> 8, n = t & 255;
        w1s[(k >> 3) * 2048 + n * 8 + (k & 7)] = f2bf(W1[t]);
    }
    if (t < 65536) {  // Wut[k][n] = sum_j W2[k][j] * W3[j][n], j<128
        int k = t >> 8, n = t & 255;
        float s = 0.0f;
        for (int j = 0; j < 128; ++j) s += W2[k * 128 + j] * W3[j * 256 + n];
        wuts[(k >> 3) * 2048 + n * 8 + (k & 7)] = f2bf(s);
    } else {          // Wvt[k][n] = sum_j W2[k][j] * W3[128+j][n]
        int i = t - 65536;
        int k = i >> 8, n = i & 255;
        float s = 0.0f;
        for (int j = 0; j < 128; ++j) s += W2[k * 128 + j] * W3[(128 + j) * 256 + n];
        wvts[(k >> 3) * 2048 + n * 8 + (k & 7)] = f2bf(s);
    }
    if (t < 256) {    // bu = b3 + b2 @ W3t
        float s = b3[t];
        for (int j = 0; j < 128; ++j) s += b2[j] * W3[j * 256 + t];
        bu[t] = s;
    } else if (t < 512) {  // bv = b2 @ W3b
        int n = t - 256;
        float s = 0.0f;
        for (int j = 0; j < 128; ++j) s += b2[j] * W3[(128 + j) * 256 + n];
        bv[n] = s;
    } else if (t < 768) {  // permuted W4: phys p -> hidden index
        int p = t - 512;
        int wq = p >> 6, local = p & 63;
        w4p[p] = W4[wq * 64 + (local & 3) * 16 + ((local >> 2) & 15)];
    }
    if (t == 0) {
        const unsigned* u = (const unsigned*)eidx;
        int all0 = 1;
        for (int i = 0; i < 32; ++i) all0 &= (u[2 * i + 1] == 0u);
        *flag = all0;
    }
}

// ---------------- node_uv: x -> relu1 -> U,V; coalesced permuted stores ---
__global__ __launch_bounds__(256, 3) void node_uv(
    const float* __restrict__ x, const float* __restrict__ b1,
    const unsigned short* __restrict__ w1s, const unsigned short* __restrict__ wuts,
    const unsigned short* __restrict__ wvts, const float* __restrict__ bu,
    const float* __restrict__ bv, unsigned short* __restrict__ Ug,
    unsigned short* __restrict__ Vg) {
    __shared__ __align__(16) unsigned short A1[64 * 136];  // 17408 B
    __shared__ __align__(16) unsigned short A2[64 * 264];  // 33792 B

    const int t = threadIdx.x, lane = t & 63, w = t >> 6;  // w: 0..3
    const int cl = lane & 15, q = lane >> 4;
    const int nb = w * 64;   // this wave's 64 N-cols
    const int m0 = blockIdx.x * 64;

    // stage x -> A1 bf16
    {
        const float4* x4 = (const float4*)x;
#pragma unroll
        for (int i = 0; i < 8; ++i) {
            int lin = i * 256 + t;
            int m = lin >> 5, c = lin & 31;
            int node = m0 + m;
            if (node > NN - 1) node = NN - 1;
            float4 v = x4[node * 32 + c];
            us4 b;
            b.x = f2bf(v.x); b.y = f2bf(v.y); b.z = f2bf(v.z); b.w = f2bf(v.w);
            *(us4*)(A1 + m * 136 + c * 4) = b;
        }
    }
    float b1v[4], buv[4], bvv[4];
#pragma unroll
    for (int nt = 0; nt < 4; ++nt) {
        int n = nb + nt * 16 + cl;
        b1v[nt] = b1[n];
        buv[nt] = bu[n];
        bvv[nt] = bv[n];
    }
    __syncthreads();

    // GEMM1: [64x128]x[128x256], B streamed from L2
    {
        f32x4 acc[4][4];
#pragma unroll
        for (int mt = 0; mt < 4; ++mt)
#pragma unroll
            for (int nt = 0; nt < 4; ++nt)
                acc[mt][nt] = (f32x4){b1v[nt], b1v[nt], b1v[nt], b1v[nt]};
#pragma unroll
        for (int s = 0; s < 4; ++s) {
            bf16x8 a[4], bw[4];
#pragma unroll
            for (int mt = 0; mt < 4; ++mt)
                a[mt] = *(const bf16x8*)(A1 + (mt * 16 + cl) * 136 + s * 32 + q * 8);
#pragma unroll
            for (int nt = 0; nt < 4; ++nt)
                bw[nt] = *(const bf16x8*)(w1s + (s * 4 + q) * 2048 +
                                          (nb + nt * 16 + cl) * 8);
#pragma unroll
            for (int mt = 0; mt < 4; ++mt)
#pragma unroll
                for (int nt = 0; nt < 4; ++nt)
                    acc[mt][nt] = __builtin_amdgcn_mfma_f32_16x16x32_bf16(
                        a[mt], bw[nt], acc[mt][nt], 0, 0, 0);
        }
        // relu -> A2
#pragma unroll
        for (int mt = 0; mt < 4; ++mt)
#pragma unroll
            for (int nt = 0; nt < 4; ++nt)
#pragma unroll
                for (int r = 0; r < 4; ++r) {
                    float v = fmaxf(acc[mt][nt][r], 0.0f);
                    A2[(mt * 16 + q * 4 + r) * 264 + nb + nt * 16 + cl] = f2bf(v);
                }
    }
    __syncthreads();

    // GEMM U then V (A2 reused); permuted ushort4 epilogue (coalesced)
#pragma unroll
    for (int pass = 0; pass < 2; ++pass) {
        const unsigned short* wt = pass ? wvts : wuts;
        unsigned short* outg = pass ? Vg : Ug;
        f32x4 acc[4][4];
#pragma unroll
        for (int mt = 0; mt < 4; ++mt)
#pragma unroll
            for (int nt = 0; nt < 4; ++nt) {
                float bb = pass ? bvv[nt] : buv[nt];
                acc[mt][nt] = (f32x4){bb, bb, bb, bb};
            }
#pragma unroll
        for (int s = 0; s < 8; ++s) {
            bf16x8 a[4], bw[4];
#pragma unroll
            for (int mt = 0; mt < 4; ++mt)
                a[mt] = *(const bf16x8*)(A2 + (mt * 16 + cl) * 264 + s * 32 + q * 8);
#pragma unroll
            for (int nt = 0; nt < 4; ++nt)
                bw[nt] = *(const bf16x8*)(wt + (s * 4 + q) * 2048 +
                                          (nb + nt * 16 + cl) * 8);
#pragma unroll
            for (int mt = 0; mt < 4; ++mt)
#pragma unroll
                for (int nt = 0; nt < 4; ++nt)
                    acc[mt][nt] = __builtin_amdgcn_mfma_f32_16x16x32_bf16(
                        a[mt], bw[nt], acc[mt][nt], 0, 0, 0);
        }
        // store: phys p = nb + cl*4 + nt  (8 B/lane, 4x128B segments/instr)
#pragma unroll
        for (int mt = 0; mt < 4; ++mt)
#pragma unroll
            for (int r = 0; r < 4; ++r) {
                int node = m0 + mt * 16 + q * 4 + r;
                if (node < NN) {
                    us4 v = {f2bf(acc[mt][0][r]), f2bf(acc[mt][1][r]),
                             f2bf(acc[mt][2][r]), f2bf(acc[mt][3][r])};
                    *(us4*)(outg + node * 256 + nb + cl * 4) = v;
                }
            }
    }
}

// ---------------- edge_pred: wide-MLP streaming gather + VALU -------------
#define TERM(uw, vw, wa, wb)                                     \
    (fmaxf(bflo(uw) + bflo(vw), 0.0f) * (wa) +                   \
     fmaxf(bfhi(uw) + bfhi(vw), 0.0f) * (wb))

// full 256-dim dot contribution for edge slot k (two uint4 halves per side)
#define EDGE_DOT(k)                                                          \
    (TERM(u0[k].x, v0[k].x, w4a[0], w4a[1]) +                                \
     TERM(u0[k].y, v0[k].y, w4a[2], w4a[3]) +                                \
     TERM(u0[k].z, v0[k].z, w4a[4], w4a[5]) +                                \
     TERM(u0[k].w, v0[k].w, w4a[6], w4a[7]) +                                \
     TERM(u1[k].x, v1[k].x, w4b[0], w4b[1]) +                                \
     TERM(u1[k].y, v1[k].y, w4b[2], w4b[3]) +                                \
     TERM(u1[k].z, v1[k].z, w4b[4], w4b[5]) +                                \
     TERM(u1[k].w, v1[k].w, w4b[6], w4b[7]))

__global__ __launch_bounds__(256, 5) void edge_pred(
    const void* __restrict__ eidx, const unsigned short* __restrict__ Ut,
    const unsigned short* __restrict__ Vt, const float* __restrict__ w4p,
    const float* __restrict__ b4, const int* __restrict__ flag,
    float* __restrict__ out) {
    const int t = threadIdx.x, lane = t & 63;
    const int cl = lane & 15, g = lane >> 4;       // 4 edge-groups of 16 lanes
    const int gwid = (blockIdx.x * 256 + t) >> 6;  // 0..8191
    const bool i64f = (*flag != 0);
    const int* ei32 = (const int*)eidx;
    const long long* ei64 = (const long long*)eidx;

    float w4a[8], w4b[8];
#pragma unroll
    for (int j = 0; j < 8; ++j) {
        w4a[j] = w4p[cl * 8 + j];
        w4b[j] = w4p[128 + cl * 8 + j];
    }
    const float b4v = b4[0];

    // 16 edges per wave-iteration: group g owns edges base + 4k + g, k=0..3.
    // NE % 16 == 0 and base < NE always => no per-edge tail guard.
    int sI[4], dI[4];
    int base = gwid * 16;  // <= 131056 < NE: every wave runs
#pragma unroll
    for (int k = 0; k < 4; ++k) {
        int e = base + 4 * k + g;
        sI[k] = i64f ? (int)ei64[e] : ei32[e];
        dI[k] = i64f ? (int)ei64[NE + e] : ei32[NE + e];
    }
    for (;;) {
        // issue all 16 gathers (independent; results all live into compute)
        uint4 u0[4], u1[4], v0[4], v1[4];
#pragma unroll
        for (int k = 0; k < 4; ++k) {
            int s = sI[k], d = dI[k];
            s = s < 0 ? 0 : (s > NN - 1 ? NN - 1 : s);
            d = d < 0 ? 0 : (d > NN - 1 ? NN - 1 : d);
            const uint4* up = (const uint4*)(Ut + (long)s * 256) + cl;
            const uint4* vp = (const uint4*)(Vt + (long)d * 256) + cl;
            u0[k] = up[0]; u1[k] = up[16];
            v0[k] = vp[0]; v1[k] = vp[16];
        }
        // prefetch next iteration's indices (breaks idx->gather serial chain)
        const int nbase = base + STEP16;
        if (nbase < NE) {
#pragma unroll
            for (int k = 0; k < 4; ++k) {
                int e = nbase + 4 * k + g;
                sI[k] = i64f ? (int)ei64[e] : ei32[e];
                dI[k] = i64f ? (int)ei64[NE + e] : ei32[NE + e];
            }
        }
        // consume in load-issue order (staggered vmcnt waits)
#pragma unroll
        for (int k = 0; k < 4; ++k) {
            float acc = EDGE_DOT(k);
            acc = row_reduce16(acc);
            if (cl == 15)
                out[base + 4 * k + g] = 1.0f / (1.0f + __expf(-(acc + b4v)));
        }
        if (nbase >= NE) break;
        base = nbase;
    }
}

extern "C" void kernel_launch(void* const* d_in, const int* in_sizes, int n_in,
                              void* d_out, int out_size, void* d_ws, size_t ws_size,
                              hipStream_t stream) {
    const float* x  = (const float*)d_in[0];
    const void*  ei = d_in[1];
    const float* W1 = (const float*)d_in[2];
    const float* b1 = (const float*)d_in[3];
    const float* W2 = (const float*)d_in[4];
    const float* b2 = (const float*)d_in[5];
    const float* W3 = (const float*)d_in[6];
    const float* b3 = (const float*)d_in[7];
    const float* W4 = (const float*)d_in[8];
    const float* b4 = (const float*)d_in[9];

    char* ws = (char*)d_ws;
    int* flag            = (int*)ws;
    unsigned short* w1s  = (unsigned short*)(ws + 256);
    unsigned short* wuts = (unsigned short*)(ws + 65792);
    unsigned short* wvts = (unsigned short*)(ws + 196864);
    float* bu            = (float*)(ws + 327936);
    float* bv            = (float*)(ws + 328960);
    float* w4p           = (float*)(ws + 329984);
    unsigned short* Ug   = (unsigned short*)(ws + 1048576);
    unsigned short* Vg   = (unsigned short*)(ws + 52248576);

    prep1<<<512, 256, 0, stream>>>(W1, W2, W3, b2, b3, W4, ei, w1s, wuts, wvts,
                                   bu, bv, w4p, flag);
    node_uv<<<NTN, 256, 0, stream>>>(x, b1, w1s, wuts, wvts, bu, bv, Ug, Vg);
    edge_pred<<<GRID_EP, 256, 0, stream>>>(ei, Ug, Vg, w4p, b4, flag, (float*)d_out);
}

// Round 3
// 299.557 us; speedup vs baseline: 1.7592x; 1.7592x over previous
//
#include <hip/hip_runtime.h>

// PPAModel: node encoder -> edge gather/concat -> edge MLP -> sigmoid
// IN=128, HID=256, OUT=128, N_NODES=100000, N_EDGES=1000000
//
// v13 (v10 node_uv + LDS-staged pipelined edge_pred):
//   v11/v12 lesson: hipcc will NOT hold wide gather results in VGPRs
//   (VGPR pinned at 48, spilled 774MB to scratch). So move the gather
//   in-flight state to LDS: __builtin_amdgcn_global_load_lds (16B/lane,
//   1KB/instr) into a per-wave 2-slot ring (4 edges x 1KB per slot),
//   hand-counted  s_waitcnt vmcnt(4)  (never 0 in the loop) keeps the
//   next slot's 4 gathers + idx prefetch in flight across iterations.
//   Consume via inline-asm ds_read_b128 (C++ LDS reads would make the
//   waitcnt pass insert a draining vmcnt(0) against the builtins), each
//   wait followed by sched_barrier(0) (rule: compiler hoists dependent
//   ops past asm waitcnt otherwise). Same bytes per lane as v10 ->
//   bitwise-identical math. LDS 32KB/block -> 5 blocks/CU.
//
// ws layout (~103.5 MB):
//   flag @ 0          w1s @ 256 (64KB)
//   wuts @ 65792 (128KB)   wvts @ 196864 (128KB)
//   bu @ 327936 (1KB)      bv @ 328960 (1KB)    w4p @ 329984 (1KB)
//   U @ 1048576 (51.2MB)   V @ 52248576 (51.2MB)

#define NN 100000
#define NE 1000000
#define NTN 1563
#define GRID_EP 1280
#define NWAVES (GRID_EP * 4)          // 5120 waves, 4 edges each per iter
#define STEP4 (NWAVES * 4)            // 20480 edges per grid-stride round
#define NIT (((NE / 4) + NWAVES - 1) / NWAVES)  // 49 iterations, all waves

typedef __attribute__((ext_vector_type(8))) __bf16 bf16x8;
typedef __attribute__((ext_vector_type(4))) float f32x4;
typedef __attribute__((ext_vector_type(4))) unsigned short us4;
typedef __attribute__((ext_vector_type(4))) unsigned int u32x4;

__device__ __forceinline__ unsigned short f2bf(float f) {
    unsigned u = __float_as_uint(f);
    return (unsigned short)((u + 0x7FFFu + ((u >> 16) & 1u)) >> 16);
}
__device__ __forceinline__ float bflo(unsigned w) {
    return __uint_as_float(w << 16);
}
__device__ __forceinline__ float bfhi(unsigned w) {
    return __uint_as_float(w & 0xffff0000u);
}

template <int CTRL>
__device__ __forceinline__ float dpp_add(float v) {
    return v + __int_as_float(__builtin_amdgcn_update_dpp(
                   0, __float_as_int(v), CTRL, 0xF, 0xF, true));
}
// sum over 16 lanes of a DPP row; valid at (lane&15)==15 (row_shr -> high lane)
__device__ __forceinline__ float row_reduce16(float v) {
    v = dpp_add<0x118>(v);
    v = dpp_add<0x114>(v);
    v = dpp_add<0x112>(v);
    v = dpp_add<0x111>(v);
    return v;
}

// ---------------- prep: W1 swizzle, Wut/Wvt bf16-swizzled, bu/bv/w4p ------
__global__ void prep1(const float* __restrict__ W1, const float* __restrict__ W2,
                      const float* __restrict__ W3, const float* __restrict__ b2,
                      const float* __restrict__ b3, const float* __restrict__ W4,
                      const void* __restrict__ eidx,
                      unsigned short* __restrict__ w1s,
                      unsigned short* __restrict__ wuts,
                      unsigned short* __restrict__ wvts, float* __restrict__ bu,
                      float* __restrict__ bv, float* __restrict__ w4p,
                      int* __restrict__ flag) {
    int t = blockIdx.x * blockDim.x + threadIdx.x;  // 131072 threads
    if (t < 32768) {  // W1 swizzle: K=128, N=256, [k/8][n][k%8]
        int k = t >> 8, n = t & 255;
        w1s[(k >> 3) * 2048 + n * 8 + (k & 7)] = f2bf(W1[t]);
    }
    if (t < 65536) {  // Wut[k][n] = sum_j W2[k][j] * W3[j][n], j<128
        int k = t >> 8, n = t & 255;
        float s = 0.0f;
        for (int j = 0; j < 128; ++j) s += W2[k * 128 + j] * W3[j * 256 + n];
        wuts[(k >> 3) * 2048 + n * 8 + (k & 7)] = f2bf(s);
    } else {          // Wvt[k][n] = sum_j W2[k][j] * W3[128+j][n]
        int i = t - 65536;
        int k = i >> 8, n = i & 255;
        float s = 0.0f;
        for (int j = 0; j < 128; ++j) s += W2[k * 128 + j] * W3[(128 + j) * 256 + n];
        wvts[(k >> 3) * 2048 + n * 8 + (k & 7)] = f2bf(s);
    }
    if (t < 256) {    // bu = b3 + b2 @ W3t
        float s = b3[t];
        for (int j = 0; j < 128; ++j) s += b2[j] * W3[j * 256 + t];
        bu[t] = s;
    } else if (t < 512) {  // bv = b2 @ W3b
        int n = t - 256;
        float s = 0.0f;
        for (int j = 0; j < 128; ++j) s += b2[j] * W3[(128 + j) * 256 + n];
        bv[n] = s;
    } else if (t < 768) {  // permuted W4: phys p -> hidden index
        int p = t - 512;
        int wq = p >> 6, local = p & 63;
        w4p[p] = W4[wq * 64 + (local & 3) * 16 + ((local >> 2) & 15)];
    }
    if (t == 0) {
        const unsigned* u = (const unsigned*)eidx;
        int all0 = 1;
        for (int i = 0; i < 32; ++i) all0 &= (u[2 * i + 1] == 0u);
        *flag = all0;
    }
}

// ---------------- node_uv: x -> relu1 -> U,V; coalesced permuted stores ---
__global__ __launch_bounds__(256, 3) void node_uv(
    const float* __restrict__ x, const float* __restrict__ b1,
    const unsigned short* __restrict__ w1s, const unsigned short* __restrict__ wuts,
    const unsigned short* __restrict__ wvts, const float* __restrict__ bu,
    const float* __restrict__ bv, unsigned short* __restrict__ Ug,
    unsigned short* __restrict__ Vg) {
    __shared__ __align__(16) unsigned short A1[64 * 136];  // 17408 B
    __shared__ __align__(16) unsigned short A2[64 * 264];  // 33792 B

    const int t = threadIdx.x, lane = t & 63, w = t >> 6;  // w: 0..3
    const int cl = lane & 15, q = lane >> 4;
    const int nb = w * 64;   // this wave's 64 N-cols
    const int m0 = blockIdx.x * 64;

    // stage x -> A1 bf16
    {
        const float4* x4 = (const float4*)x;
#pragma unroll
        for (int i = 0; i < 8; ++i) {
            int lin = i * 256 + t;
            int m = lin >> 5, c = lin & 31;
            int node = m0 + m;
            if (node > NN - 1) node = NN - 1;
            float4 v = x4[node * 32 + c];
            us4 b;
            b.x = f2bf(v.x); b.y = f2bf(v.y); b.z = f2bf(v.z); b.w = f2bf(v.w);
            *(us4*)(A1 + m * 136 + c * 4) = b;
        }
    }
    float b1v[4], buv[4], bvv[4];
#pragma unroll
    for (int nt = 0; nt < 4; ++nt) {
        int n = nb + nt * 16 + cl;
        b1v[nt] = b1[n];
        buv[nt] = bu[n];
        bvv[nt] = bv[n];
    }
    __syncthreads();

    // GEMM1: [64x128]x[128x256], B streamed from L2
    {
        f32x4 acc[4][4];
#pragma unroll
        for (int mt = 0; mt < 4; ++mt)
#pragma unroll
            for (int nt = 0; nt < 4; ++nt)
                acc[mt][nt] = (f32x4){b1v[nt], b1v[nt], b1v[nt], b1v[nt]};
#pragma unroll
        for (int s = 0; s < 4; ++s) {
            bf16x8 a[4], bw[4];
#pragma unroll
            for (int mt = 0; mt < 4; ++mt)
                a[mt] = *(const bf16x8*)(A1 + (mt * 16 + cl) * 136 + s * 32 + q * 8);
#pragma unroll
            for (int nt = 0; nt < 4; ++nt)
                bw[nt] = *(const bf16x8*)(w1s + (s * 4 + q) * 2048 +
                                          (nb + nt * 16 + cl) * 8);
#pragma unroll
            for (int mt = 0; mt < 4; ++mt)
#pragma unroll
                for (int nt = 0; nt < 4; ++nt)
                    acc[mt][nt] = __builtin_amdgcn_mfma_f32_16x16x32_bf16(
                        a[mt], bw[nt], acc[mt][nt], 0, 0, 0);
        }
        // relu -> A2
#pragma unroll
        for (int mt = 0; mt < 4; ++mt)
#pragma unroll
            for (int nt = 0; nt < 4; ++nt)
#pragma unroll
                for (int r = 0; r < 4; ++r) {
                    float v = fmaxf(acc[mt][nt][r], 0.0f);
                    A2[(mt * 16 + q * 4 + r) * 264 + nb + nt * 16 + cl] = f2bf(v);
                }
    }
    __syncthreads();

    // GEMM U then V (A2 reused); permuted ushort4 epilogue (coalesced)
#pragma unroll
    for (int pass = 0; pass < 2; ++pass) {
        const unsigned short* wt = pass ? wvts : wuts;
        unsigned short* outg = pass ? Vg : Ug;
        f32x4 acc[4][4];
#pragma unroll
        for (int mt = 0; mt < 4; ++mt)
#pragma unroll
            for (int nt = 0; nt < 4; ++nt) {
                float bb = pass ? bvv[nt] : buv[nt];
                acc[mt][nt] = (f32x4){bb, bb, bb, bb};
            }
#pragma unroll
        for (int s = 0; s < 8; ++s) {
            bf16x8 a[4], bw[4];
#pragma unroll
            for (int mt = 0; mt < 4; ++mt)
                a[mt] = *(const bf16x8*)(A2 + (mt * 16 + cl) * 264 + s * 32 + q * 8);
#pragma unroll
            for (int nt = 0; nt < 4; ++nt)
                bw[nt] = *(const bf16x8*)(wt + (s * 4 + q) * 2048 +
                                          (nb + nt * 16 + cl) * 8);
#pragma unroll
            for (int mt = 0; mt < 4; ++mt)
#pragma unroll
                for (int nt = 0; nt < 4; ++nt)
                    acc[mt][nt] = __builtin_amdgcn_mfma_f32_16x16x32_bf16(
                        a[mt], bw[nt], acc[mt][nt], 0, 0, 0);
        }
        // store: phys p = nb + cl*4 + nt  (8 B/lane, 4x128B segments/instr)
#pragma unroll
        for (int mt = 0; mt < 4; ++mt)
#pragma unroll
            for (int r = 0; r < 4; ++r) {
                int node = m0 + mt * 16 + q * 4 + r;
                if (node < NN) {
                    us4 v = {f2bf(acc[mt][0][r]), f2bf(acc[mt][1][r]),
                             f2bf(acc[mt][2][r]), f2bf(acc[mt][3][r])};
                    *(us4*)(outg + node * 256 + nb + cl * 4) = v;
                }
            }
    }
}

// ---------------- edge_pred: LDS-staged pipelined gather + VALU -----------
#define TERM(uw, vw, wa, wb)                                     \
    (fmaxf(bflo(uw) + bflo(vw), 0.0f) * (wa) +                   \
     fmaxf(bfhi(uw) + bfhi(vw), 0.0f) * (wb))

#define EDOT(u0, u1, v0, v1)                                                 \
    (TERM(u0.x, v0.x, w4a[0], w4a[1]) + TERM(u0.y, v0.y, w4a[2], w4a[3]) +   \
     TERM(u0.z, v0.z, w4a[4], w4a[5]) + TERM(u0.w, v0.w, w4a[6], w4a[7]) +   \
     TERM(u1.x, v1.x, w4b[0], w4b[1]) + TERM(u1.y, v1.y, w4b[2], w4b[3]) +   \
     TERM(u1.z, v1.z, w4b[4], w4b[5]) + TERM(u1.w, v1.w, w4b[6], w4b[7]))

// per-lane indices for this lane's group-edge (16 lanes broadcast-load same addr)
#define LDIDX(e, s, d)                                                       \
    {                                                                        \
        int ee = (e);                                                        \
        if (i64f) {                                                          \
            s = (int)ei64[ee];                                               \
            d = (int)ei64[NE + ee];                                          \
        } else {                                                             \
            s = ei32[ee];                                                    \
            d = ei32[NE + ee];                                               \
        }                                                                    \
    }

// one 16B/lane global->LDS DMA; LDS dest is wave-uniform base + lane*16
#define GL16(gp, lp)                                                         \
    __builtin_amdgcn_global_load_lds(                                        \
        (const __attribute__((address_space(1))) void*)(gp),                 \
        (__attribute__((address_space(3))) void*)(lp), 16, 0, 0)

// issue the 4 gathers (U row halves + V row halves) for slot `slot`.
// lane (g,cl) sources its group's row bytes [cl*16,+16); dest lane*16 =
// g*256+cl*16 -> consume mapping matches v10's register layout bit-for-bit.
#define ISSUE4(slot, si, di)                                                 \
    {                                                                        \
        int s_ = (si), d_ = (di);                                            \
        s_ = s_ < 0 ? 0 : (s_ > NN - 1 ? NN - 1 : s_);                       \
        d_ = d_ < 0 ? 0 : (d_ > NN - 1 ? NN - 1 : d_);                       \
        const char* up_ = (const char*)Ut + (long long)s_ * 512 + cl * 16;   \
        const char* vp_ = (const char*)Vt + (long long)d_ * 512 + cl * 16;   \
        char* l_ = &smem[w][slot][0];                                        \
        GL16(up_, l_);                                                       \
        GL16(up_ + 256, l_ + 1024);                                          \
        GL16(vp_, l_ + 2048);                                                \
        GL16(vp_ + 256, l_ + 3072);                                          \
    }

__global__ __launch_bounds__(256, 5) void edge_pred(
    const void* __restrict__ eidx, const unsigned short* __restrict__ Ut,
    const unsigned short* __restrict__ Vt, const float* __restrict__ w4p,
    const float* __restrict__ b4, const int* __restrict__ flag,
    float* __restrict__ out) {
    // per-wave 2-slot ring: slot = 4 edges x (U0|U1|V0|V1) x 1KB = 4KB
    __shared__ __align__(1024) char smem[4][2][4096];  // 32 KB -> 5 blk/CU

    const int t = threadIdx.x, lane = t & 63, w = t >> 6;
    const int cl = lane & 15, g = lane >> 4;        // 4 edge-groups of 16 lanes
    const int gwid = (blockIdx.x << 2) + w;         // 0..NWAVES-1
    const bool i64f = (*flag != 0);
    const int* ei32 = (const int*)eidx;
    const long long* ei64 = (const long long*)eidx;

    float w4a[8], w4b[8];
#pragma unroll
    for (int j = 0; j < 8; ++j) {
        w4a[j] = w4p[cl * 8 + j];
        w4b[j] = w4p[128 + cl * 8 + j];
    }
    const float b4v = b4[0];
    // LDS apertures are 4GB-aligned: low 32 bits of a generic LDS pointer
    // are the LDS byte offset -> usable as ds_read vaddr.
    const unsigned smoff = (unsigned)(size_t)(&smem[w][0][0]);

    // ---- prologue: fill both slots, prefetch idx for slot+2 ----
    int b = gwid * 4;  // <= 20476 < NE; b, b+STEP4, b+2*STEP4 all < NE
    int sP, dP;        // indices pending for base b+2*STEP4
    {
        int s0, d0, s1, d1;
        LDIDX(b + g, s0, d0);
        LDIDX(b + STEP4 + g, s1, d1);
        ISSUE4(0, s0, d0);
        ISSUE4(1, s1, d1);
        LDIDX(b + 2 * STEP4 + g, sP, dP);
    }
    int cur = 0;
    for (int it = 0; it < NIT; ++it) {
        // retire slot cur's 4 gathers: only the other slot's 4 gathers are
        // provably newer (idx loads/out stores may float -> over-wait only).
        asm volatile("s_waitcnt vmcnt(4)" ::: "memory");
        __builtin_amdgcn_sched_barrier(0);
        const unsigned a = smoff + (unsigned)(cur << 12) + (unsigned)(lane * 16);
        u32x4 u0, u1, v0, v1;
        asm volatile("ds_read_b128 %0, %1" : "=v"(u0) : "v"(a));
        asm volatile("ds_read_b128 %0, %1 offset:1024" : "=v"(u1) : "v"(a));
        asm volatile("ds_read_b128 %0, %1 offset:2048" : "=v"(v0) : "v"(a));
        asm volatile("ds_read_b128 %0, %1 offset:3072" : "=v"(v1) : "v"(a));
        asm volatile("s_waitcnt lgkmcnt(0)" ::: "memory");
        __builtin_amdgcn_sched_barrier(0);

        float acc = EDOT(u0, u1, v0, v1);
        acc = row_reduce16(acc);
        if (b < NE && cl == 15)
            out[b + g] = 1.0f / (1.0f + __expf(-(acc + b4v)));

        // prefetch idx for b+3*STEP4 (clamped base past end: harmless reload
        // of edge 0..3), then refill the just-consumed slot for b+2*STEP4.
        int bn = b + 3 * STEP4;
        int sN, dN;
        LDIDX((bn < NE ? bn : 0) + g, sN, dN);
        ISSUE4(cur, sP, dP);
        sP = sN;
        dP = dN;
        cur ^= 1;
        b += STEP4;
    }
    // drain: stray LDS-writing loads must not land after LDS is reallocated
    asm volatile("s_waitcnt vmcnt(0)" ::: "memory");
}

extern "C" void kernel_launch(void* const* d_in, const int* in_sizes, int n_in,
                              void* d_out, int out_size, void* d_ws, size_t ws_size,
                              hipStream_t stream) {
    const float* x  = (const float*)d_in[0];
    const void*  ei = d_in[1];
    const float* W1 = (const float*)d_in[2];
    const float* b1 = (const float*)d_in[3];
    const float* W2 = (const float*)d_in[4];
    const float* b2 = (const float*)d_in[5];
    const float* W3 = (const float*)d_in[6];
    const float* b3 = (const float*)d_in[7];
    const float* W4 = (const float*)d_in[8];
    const float* b4 = (const float*)d_in[9];

    char* ws = (char*)d_ws;
    int* flag            = (int*)ws;
    unsigned short* w1s  = (unsigned short*)(ws + 256);
    unsigned short* wuts = (unsigned short*)(ws + 65792);
    unsigned short* wvts = (unsigned short*)(ws + 196864);
    float* bu            = (float*)(ws + 327936);
    float* bv            = (float*)(ws + 328960);
    float* w4p           = (float*)(ws + 329984);
    unsigned short* Ug   = (unsigned short*)(ws + 1048576);
    unsigned short* Vg   = (unsigned short*)(ws + 52248576);

    prep1<<<512, 256, 0, stream>>>(W1, W2, W3, b2, b3, W4, ei, w1s, wuts, wvts,
                                   bu, bv, w4p, flag);
    node_uv<<<NTN, 256, 0, stream>>>(x, b1, w1s, wuts, wvts, bu, bv, Ug, Vg);
    edge_pred<<<GRID_EP, 256, 0, stream>>>(ei, Ug, Vg, w4p, b4, flag, (float*)d_out);
}